// Round 1
// baseline (3668.078 us; speedup 1.0000x reference)
//
#include <hip/hip_runtime.h>
#include <stdint.h>

// Problem constants
#define HH    1024
#define H3    3072
#define NB    8      // batch
#define SEQ   256
#define MTOK  2048   // B*S
#define VOCAB 32000

typedef __attribute__((ext_vector_type(8))) short short8;
typedef __attribute__((ext_vector_type(4))) float floatx4;

__device__ __forceinline__ uint16_t f2bf(float f) {
    // fp32 -> bf16 round-to-nearest-even
    uint32_t u = __float_as_uint(f);
    return (uint16_t)((u + 0x7FFFu + ((u >> 16) & 1u)) >> 16);
}

__device__ __forceinline__ float sigm(float x) { return 1.0f / (1.0f + __expf(-x)); }

// ---------------------------------------------------------------------------
// Embedding gather -> bf16 rows [2048][1024], m = b*256 + s (row-major like out)
__global__ void kEmbed(const int* __restrict__ x, const float* __restrict__ emb,
                       uint16_t* __restrict__ xe) {
    int m = blockIdx.x;
    int tok = x[m];                       // x flat [b][s] == m
    float4 v = *(const float4*)(emb + (size_t)tok * HH + threadIdx.x * 4);
    ushort4 o;
    o.x = f2bf(v.x); o.y = f2bf(v.y); o.z = f2bf(v.z); o.w = f2bf(v.w);
    *(ushort4*)(xe + (size_t)m * HH + threadIdx.x * 4) = o;
}

// ---------------------------------------------------------------------------
// Tiled MFMA GEMM: C[M][N] = A[M][1024](bf16) * W[N][*](fp32, cols 0..1023)^T + bias
// 128x128 tile / WG, BK=64, 4 waves in 2x2, 16x16x32 bf16 MFMA.
// LDS tiles XOR-swizzled: slot(row, c) at byte row*128 + ((c ^ (row&7))*16).
__global__ __launch_bounds__(256) void kGemm(
    const uint16_t* __restrict__ A, const float* __restrict__ W,
    const float* __restrict__ bias, float* __restrict__ C,
    int N, int strideW) {
    __shared__ uint16_t lA[128 * 64];
    __shared__ uint16_t lB[128 * 64];

    const int tid  = threadIdx.x;
    const int rowT = blockIdx.y * 128;   // M base
    const int colT = blockIdx.x * 128;   // N base
    const int pos  = tid & 7;
    const int r8   = (tid >> 3) & 7;
    const int ca   = pos ^ r8;           // chunk this thread stages (swizzle)
    const int lane = tid & 63, w = tid >> 6;
    const int wm = (w >> 1) * 64, wn = (w & 1) * 64;
    const int l15 = lane & 15, l4 = lane >> 4;

    floatx4 acc[4][4];
    for (int a = 0; a < 4; a++)
        for (int b = 0; b < 4; b++)
            acc[a][b] = (floatx4){0.f, 0.f, 0.f, 0.f};

    for (int it = 0; it < 16; ++it) {
        const int kB = it * 64;
        // global -> regs (A: bf16 16B chunk; W: 8 fp32 -> bf16)
        uint4 av[4]; uint4 bv[4];
        for (int i = 0; i < 4; i++) {
            int row = i * 32 + (tid >> 3);
            av[i] = *(const uint4*)(A + (size_t)(rowT + row) * HH + kB + ca * 8);
            const float* wp = W + (size_t)(colT + row) * strideW + kB + ca * 8;
            float4 w0 = *(const float4*)wp;
            float4 w1 = *(const float4*)(wp + 4);
            uint4 pk;
            pk.x = (uint32_t)f2bf(w0.x) | ((uint32_t)f2bf(w0.y) << 16);
            pk.y = (uint32_t)f2bf(w0.z) | ((uint32_t)f2bf(w0.w) << 16);
            pk.z = (uint32_t)f2bf(w1.x) | ((uint32_t)f2bf(w1.y) << 16);
            pk.w = (uint32_t)f2bf(w1.z) | ((uint32_t)f2bf(w1.w) << 16);
            bv[i] = pk;
        }
        __syncthreads();                 // previous iter's reads done
        for (int i = 0; i < 4; i++) {
            int slot = i * 256 + tid;
            *(uint4*)(lA + slot * 8) = av[i];
            *(uint4*)(lB + slot * 8) = bv[i];
        }
        __syncthreads();
        for (int ks = 0; ks < 2; ++ks) {
            short8 af[4], bf_[4];
            int kc = ks * 4 + l4;
            for (int mt = 0; mt < 4; mt++) {
                int row = wm + mt * 16 + l15;
                af[mt] = *(const short8*)(lA + row * 64 + ((kc ^ (row & 7)) * 8));
            }
            for (int nt = 0; nt < 4; nt++) {
                int row = wn + nt * 16 + l15;
                bf_[nt] = *(const short8*)(lB + row * 64 + ((kc ^ (row & 7)) * 8));
            }
            for (int mt = 0; mt < 4; mt++)
                for (int nt = 0; nt < 4; nt++)
                    acc[mt][nt] = __builtin_amdgcn_mfma_f32_16x16x32_bf16(
                        af[mt], bf_[nt], acc[mt][nt], 0, 0, 0);
        }
    }
    // epilogue: D row=(lane>>4)*4+r, col=lane&15 (m89/m91-verified mapping)
    for (int nt = 0; nt < 4; nt++) {
        int col = colT + wn + nt * 16 + l15;
        float bval = bias[col];
        for (int mt = 0; mt < 4; mt++) {
            int row0 = rowT + wm + mt * 16 + l4 * 4;
            for (int r = 0; r < 4; r++)
                C[(size_t)(row0 + r) * N + col] = acc[mt][nt][r] + bval;
        }
    }
}

// ---------------------------------------------------------------------------
// One low-GRU step (fp32). 256 WGs x 256 thr; WG owns 4 hidden j (1 per wave).
// gi (token part incl. l_bih) precomputed in gix; h_h part in gih.
__global__ __launch_bounds__(256) void kStep(
    const float* __restrict__ Whh, const float* __restrict__ bhh,
    const float* __restrict__ gix, const float* __restrict__ gih,
    const float* __restrict__ hcur, float* __restrict__ hnxt,
    uint16_t* __restrict__ hs, int s) {
    __shared__ float hsm[NB * HH];       // 32 KB
    int tid = threadIdx.x;
    for (int b = 0; b < NB; b++)
        *(float4*)(hsm + b * HH + tid * 4) = *(const float4*)(hcur + b * HH + tid * 4);
    __syncthreads();

    int lane = tid & 63, w = tid >> 6;
    int j = blockIdx.x * 4 + w;
    const float* wr = Whh + (size_t)j * HH;
    const float* wz = Whh + (size_t)(HH + j) * HH;
    const float* wn = Whh + (size_t)(2 * HH + j) * HH;
    float pr[NB], pz[NB], pn[NB];
    for (int b = 0; b < NB; b++) { pr[b] = 0.f; pz[b] = 0.f; pn[b] = 0.f; }
    for (int c = 0; c < 4; c++) {
        int k0 = c * 256 + lane * 4;
        float4 vr = *(const float4*)(wr + k0);
        float4 vz = *(const float4*)(wz + k0);
        float4 vn = *(const float4*)(wn + k0);
        for (int b = 0; b < NB; b++) {
            float4 hv = *(const float4*)(hsm + b * HH + k0);
            pr[b] += vr.x * hv.x + vr.y * hv.y + vr.z * hv.z + vr.w * hv.w;
            pz[b] += vz.x * hv.x + vz.y * hv.y + vz.z * hv.z + vz.w * hv.w;
            pn[b] += vn.x * hv.x + vn.y * hv.y + vn.z * hv.z + vn.w * hv.w;
        }
    }
    for (int off = 1; off < 64; off <<= 1)
        for (int b = 0; b < NB; b++) {
            pr[b] += __shfl_xor(pr[b], off, 64);
            pz[b] += __shfl_xor(pz[b], off, 64);
            pn[b] += __shfl_xor(pn[b], off, 64);
        }
    if (lane < NB) {
        int b = lane;
        size_t m = (size_t)b * SEQ + s;
        float ir = gix[m * H3 + j]          + gih[b * H3 + j];
        float iz = gix[m * H3 + HH + j]     + gih[b * H3 + HH + j];
        float in_ = gix[m * H3 + 2 * HH + j] + gih[b * H3 + 2 * HH + j];
        float hr = pr[b] + bhh[j];
        float hz = pz[b] + bhh[HH + j];
        float hn = pn[b] + bhh[2 * HH + j];
        float r = sigm(ir + hr);
        float z = sigm(iz + hz);
        float n = tanhf(in_ + r * hn);
        float hnew = (1.f - z) * n + z * hsm[b * HH + j];
        hnxt[b * HH + j] = hnew;
        hs[m * HH + j] = f2bf(hnew);
    }
}

// ---------------------------------------------------------------------------
// High-GRU update: h_h' = GRU(input=h_l_end via h_Wih, state=h_h via h_Whh)
__global__ __launch_bounds__(256) void kHGRU(
    const float* __restrict__ Wih, const float* __restrict__ Whh,
    const float* __restrict__ bih, const float* __restrict__ bhh,
    const float* __restrict__ xl, const float* __restrict__ hcur,
    float* __restrict__ hnxt) {
    __shared__ float sx[NB * HH];
    __shared__ float sh[NB * HH];        // 64 KB total
    int tid = threadIdx.x;
    for (int b = 0; b < NB; b++) {
        *(float4*)(sx + b * HH + tid * 4) = *(const float4*)(xl + b * HH + tid * 4);
        *(float4*)(sh + b * HH + tid * 4) = *(const float4*)(hcur + b * HH + tid * 4);
    }
    __syncthreads();
    int lane = tid & 63, w = tid >> 6;
    int j = blockIdx.x * 4 + w;
    const float* wir = Wih + (size_t)j * HH;
    const float* wiz = Wih + (size_t)(HH + j) * HH;
    const float* win = Wih + (size_t)(2 * HH + j) * HH;
    const float* whr = Whh + (size_t)j * HH;
    const float* whz = Whh + (size_t)(HH + j) * HH;
    const float* whn = Whh + (size_t)(2 * HH + j) * HH;
    float air[NB], aiz[NB], ain[NB], ahr[NB], ahz[NB], ahn[NB];
    for (int b = 0; b < NB; b++) { air[b]=aiz[b]=ain[b]=ahr[b]=ahz[b]=ahn[b]=0.f; }
    for (int c = 0; c < 4; c++) {
        int k0 = c * 256 + lane * 4;
        float4 vir = *(const float4*)(wir + k0);
        float4 viz = *(const float4*)(wiz + k0);
        float4 vin = *(const float4*)(win + k0);
        float4 vhr = *(const float4*)(whr + k0);
        float4 vhz = *(const float4*)(whz + k0);
        float4 vhn = *(const float4*)(whn + k0);
        for (int b = 0; b < NB; b++) {
            float4 xv = *(const float4*)(sx + b * HH + k0);
            float4 hv = *(const float4*)(sh + b * HH + k0);
            air[b] += vir.x*xv.x + vir.y*xv.y + vir.z*xv.z + vir.w*xv.w;
            aiz[b] += viz.x*xv.x + viz.y*xv.y + viz.z*xv.z + viz.w*xv.w;
            ain[b] += vin.x*xv.x + vin.y*xv.y + vin.z*xv.z + vin.w*xv.w;
            ahr[b] += vhr.x*hv.x + vhr.y*hv.y + vhr.z*hv.z + vhr.w*hv.w;
            ahz[b] += vhz.x*hv.x + vhz.y*hv.y + vhz.z*hv.z + vhz.w*hv.w;
            ahn[b] += vhn.x*hv.x + vhn.y*hv.y + vhn.z*hv.z + vhn.w*hv.w;
        }
    }
    for (int off = 1; off < 64; off <<= 1)
        for (int b = 0; b < NB; b++) {
            air[b] += __shfl_xor(air[b], off, 64);
            aiz[b] += __shfl_xor(aiz[b], off, 64);
            ain[b] += __shfl_xor(ain[b], off, 64);
            ahr[b] += __shfl_xor(ahr[b], off, 64);
            ahz[b] += __shfl_xor(ahz[b], off, 64);
            ahn[b] += __shfl_xor(ahn[b], off, 64);
        }
    if (lane < NB) {
        int b = lane;
        float ir = air[b] + bih[j],      hr = ahr[b] + bhh[j];
        float iz = aiz[b] + bih[HH + j], hz = ahz[b] + bhh[HH + j];
        float in_ = ain[b] + bih[2*HH+j], hn = ahn[b] + bhh[2*HH+j];
        float r = sigm(ir + hr);
        float z = sigm(iz + hz);
        float n = tanhf(in_ + r * hn);
        hnxt[b * HH + j] = (1.f - z) * n + z * sh[b * HH + j];
    }
}

// ---------------------------------------------------------------------------
// gih[b][n] = sum_k h_h[b][k] * l_Wih[n][1024+k]   (Wcol = l_Wih + 1024, stride 2048)
__global__ __launch_bounds__(256) void kGih(
    const float* __restrict__ Wcol, const float* __restrict__ hh,
    float* __restrict__ gih) {
    __shared__ float sh[NB * HH];
    int tid = threadIdx.x;
    for (int b = 0; b < NB; b++)
        *(float4*)(sh + b * HH + tid * 4) = *(const float4*)(hh + b * HH + tid * 4);
    __syncthreads();
    int lane = tid & 63, w = tid >> 6;
    int nbase = blockIdx.x * 12 + w * 3;   // 3 rows per wave, 12 per WG, 256 WGs
    const float* w0 = Wcol + (size_t)(nbase + 0) * 2048;
    const float* w1 = Wcol + (size_t)(nbase + 1) * 2048;
    const float* w2 = Wcol + (size_t)(nbase + 2) * 2048;
    float a0[NB], a1[NB], a2[NB];
    for (int b = 0; b < NB; b++) { a0[b] = a1[b] = a2[b] = 0.f; }
    for (int c = 0; c < 4; c++) {
        int k0 = c * 256 + lane * 4;
        float4 v0 = *(const float4*)(w0 + k0);
        float4 v1 = *(const float4*)(w1 + k0);
        float4 v2 = *(const float4*)(w2 + k0);
        for (int b = 0; b < NB; b++) {
            float4 hv = *(const float4*)(sh + b * HH + k0);
            a0[b] += v0.x*hv.x + v0.y*hv.y + v0.z*hv.z + v0.w*hv.w;
            a1[b] += v1.x*hv.x + v1.y*hv.y + v1.z*hv.z + v1.w*hv.w;
            a2[b] += v2.x*hv.x + v2.y*hv.y + v2.z*hv.z + v2.w*hv.w;
        }
    }
    for (int off = 1; off < 64; off <<= 1)
        for (int b = 0; b < NB; b++) {
            a0[b] += __shfl_xor(a0[b], off, 64);
            a1[b] += __shfl_xor(a1[b], off, 64);
            a2[b] += __shfl_xor(a2[b], off, 64);
        }
    if (lane < NB) {
        int b = lane;
        gih[b * H3 + nbase + 0] = a0[b];
        gih[b * H3 + nbase + 1] = a1[b];
        gih[b * H3 + nbase + 2] = a2[b];
    }
}

// ---------------------------------------------------------------------------
__global__ void kTail(const float* __restrict__ hl, const float* __restrict__ hh,
                      float* __restrict__ dst) {
    int i = blockIdx.x * 256 + threadIdx.x;
    if (i < NB * HH) dst[i] = hl[i];
    else if (i < 2 * NB * HH) dst[i] = hh[i - NB * HH];
}

// ---------------------------------------------------------------------------
extern "C" void kernel_launch(void* const* d_in, const int* in_sizes, int n_in,
                              void* d_out, int out_size, void* d_ws, size_t ws_size,
                              hipStream_t stream) {
    const int*   x    = (const int*)  d_in[0];
    const float* hl0  = (const float*)d_in[1];
    const float* hh0  = (const float*)d_in[2];
    const float* emb  = (const float*)d_in[3];
    const float* lWih = (const float*)d_in[4];   // [3072][2048]
    const float* lWhh = (const float*)d_in[5];   // [3072][1024]
    const float* lbih = (const float*)d_in[6];
    const float* lbhh = (const float*)d_in[7];
    const float* hWih = (const float*)d_in[8];
    const float* hWhh = (const float*)d_in[9];
    const float* hbih = (const float*)d_in[10];
    const float* hbhh = (const float*)d_in[11];
    const float* outW = (const float*)d_in[12];  // [32000][1024]
    const float* outb = (const float*)d_in[13];
    float* out = (float*)d_out;

    char* p = (char*)d_ws;
    float* gix = (float*)p;        p += (size_t)MTOK * H3 * 4;   // 25.2 MB
    float* gih = (float*)p;        p += (size_t)NB * H3 * 4;
    float* hbufL = (float*)p;      p += 2 * (size_t)NB * HH * 4; // ping-pong
    float* hbufH = (float*)p;      p += 2 * (size_t)NB * HH * 4;
    uint16_t* hs = (uint16_t*)p;   p += (size_t)MTOK * HH * 2;   // 4.2 MB
    uint16_t* xe = (uint16_t*)p;   p += (size_t)MTOK * HH * 2;

    // init states from inputs (general: nonzero inits handled)
    hipMemcpyAsync(hbufL, hl0, (size_t)NB * HH * 4, hipMemcpyDeviceToDevice, stream);
    hipMemcpyAsync(hbufH, hh0, (size_t)NB * HH * 4, hipMemcpyDeviceToDevice, stream);

    kEmbed<<<MTOK, 256, 0, stream>>>(x, emb, xe);
    // gi_x = x_emb @ l_Wih[:, :H].T + l_bih  (bias folded here once)
    kGemm<<<dim3(H3 / 128, MTOK / 128), 256, 0, stream>>>(xe, lWih, lbih, gix, H3, 2048);
    // gih for block 0 from h_h_init
    kGih<<<256, 256, 0, stream>>>(lWih + HH, hbufH, gih);

    for (int blk = 0; blk < 64; ++blk) {
        for (int t = 0; t < 4; ++t) {
            int g = blk * 4 + t;
            const float* hc = hbufL + (g & 1) * NB * HH;
            float* hn = hbufL + ((g + 1) & 1) * NB * HH;
            kStep<<<256, 256, 0, stream>>>(lWhh, lbhh, gix, gih, hc, hn, hs, g);
        }
        // h_l parity returns to buf0 every block (4 steps)
        const float* hhc = hbufH + (blk & 1) * NB * HH;
        float* hhn = hbufH + ((blk + 1) & 1) * NB * HH;
        kHGRU<<<256, 256, 0, stream>>>(hWih, hWhh, hbih, hbhh, hbufL, hhc, hhn);
        if (blk < 63)
            kGih<<<256, 256, 0, stream>>>(lWih + HH, hhn, gih);
    }

    // logits = hs @ out_W.T + out_b
    kGemm<<<dim3(VOCAB / 128, MTOK / 128), 256, 0, stream>>>(hs, outW, outb, out, VOCAB, 1024);
    // final h_l (buf0 after 256 steps), h_h (buf0 after 64 blocks)
    kTail<<<64, 256, 0, stream>>>(hbufL, hbufH, out + (size_t)MTOK * VOCAB);
}